// Round 4
// baseline (73.176 us; speedup 1.0000x reference)
//
#include <hip/hip_runtime.h>
#include <math.h>

#define BATCH 16
#define HH 512
#define WW 512
#define PLANE ((size_t)HH * WW)
#define NELEM ((size_t)BATCH * 3 * PLANE)

// Quant divisor tables, reference's .T applied: QT[u][v] (small ints, exact f32)
__constant__ float QYT[8][8] = {
  {16,12,14,14,18,24,49,72},
  {11,12,13,17,22,35,64,92},
  {10,14,16,22,37,55,78,95},
  {16,19,24,29,56,64,87,98},
  {24,26,40,51,68,81,103,112},
  {40,58,57,87,109,104,121,100},
  {51,60,69,80,103,113,120,103},
  {61,55,56,62,77,92,101,99},
};
__constant__ float QCT[8][8] = {
  {17,18,24,47,99,99,99,99},
  {18,21,26,66,99,99,99,99},
  {24,26,56,99,99,99,99,99},
  {47,66,99,99,99,99,99,99},
  {99,99,99,99,99,99,99,99},
  {99,99,99,99,99,99,99,99},
  {99,99,99,99,99,99,99,99},
  {99,99,99,99,99,99,99,99},
};

__device__ __forceinline__ float alphaf(int i) {
  // f32(1.0/np.sqrt(2.0)) = 0x3F3504F3
  return (i == 0) ? 0.70710678118654746f : 1.0f;
}

extern "C" __global__ __launch_bounds__(256)
void diffjpeg_kernel(const float* __restrict__ x, float* __restrict__ out) {
  __shared__ float Ys[64][68];   // 64x64 luma tile, padded stride
  __shared__ float Cbs[32][36];  // 32x32 chroma tiles
  __shared__ float Crs[32][36];
  __shared__ float Cs[64];       // Cs[a*8+b] = f32 _COS[a][b] (numpy bit-match)

  const int blk = blockIdx.x;
  const int b   = blk >> 6;
  const int t   = blk & 63;
  const int ty  = t >> 3, tx = t & 7;
  const int row0 = ty * 64, col0 = tx * 64;
  const int tid = threadIdx.x;

  // ---- phase 0: numpy-bitwise cos table ----
  // arg chain in f32 exactly as numpy: (2a+1)*b exact, * f32(pi), / 16 (exact)
  if (tid < 64) {
    int a = tid >> 3, bb = tid & 7;
    float t2 = (float)((2 * a + 1) * bb);                       // exact int
    float t3 = __fmul_rn(t2, 3.14159265358979323846f);          // f32(pi) CR
    float t4 = __fmul_rn(t3, 0.0625f);                          // /16, exact
    Cs[tid] = (float)cos((double)t4);                           // CR f32 cos
  }

  const float* Rp = x + (size_t)(b * 3 + 0) * PLANE;
  const float* Gp = x + (size_t)(b * 3 + 1) * PLANE;
  const float* Bp = x + (size_t)(b * 3 + 2) * PLANE;

  // ---- phase 1: x*255 -> sgemm-FMA YCC -> +128 -> 2x2 mean (seq order) ----
  #pragma unroll
  for (int i = 0; i < 4; ++i) {
    int q  = tid + i * 256;          // quad 0..1023 (32x32 quads of 2x2 px)
    int qy = q >> 5, qx = q & 31;
    size_t base = (size_t)(row0 + 2 * qy) * WW + (col0 + 2 * qx);
    float2 r0 = *(const float2*)(Rp + base);
    float2 r1 = *(const float2*)(Rp + base + WW);
    float2 g0 = *(const float2*)(Gp + base);
    float2 g1 = *(const float2*)(Gp + base + WW);
    float2 b0 = *(const float2*)(Bp + base);
    float2 b1 = *(const float2*)(Bp + base + WW);

    float rf[4] = {r0.x, r0.y, r1.x, r1.y};
    float gf[4] = {g0.x, g0.y, g1.x, g1.y};
    float bf[4] = {b0.x, b0.y, b1.x, b1.y};
    float Yv[4], CB[4], CR[4];
    #pragma unroll
    for (int j = 0; j < 4; ++j) {
      float R  = __fmul_rn(rf[j], 255.0f);
      float G  = __fmul_rn(gf[j], 255.0f);
      float Bv = __fmul_rn(bf[j], 255.0f);
      // sgemm K=3: acc = fma(B,m2, fma(G,m1, round(R*m0))); then +shift
      Yv[j] = __fmaf_rn(Bv, 0.114f, __fmaf_rn(G, 0.587f, __fmul_rn(R, 0.299f)));
      CB[j] = __fadd_rn(
          __fmaf_rn(Bv, 0.5f, __fmaf_rn(G, -0.331264f, __fmul_rn(R, -0.168736f))),
          128.0f);
      CR[j] = __fadd_rn(
          __fmaf_rn(Bv, -0.081312f, __fmaf_rn(G, -0.418688f, __fmul_rn(R, 0.5f))),
          128.0f);
    }

    Ys[2 * qy    ][2 * qx]     = Yv[0];
    Ys[2 * qy    ][2 * qx + 1] = Yv[1];
    Ys[2 * qy + 1][2 * qx]     = Yv[2];
    Ys[2 * qy + 1][2 * qx + 1] = Yv[3];

    // np.mean(axis=(2,4)): memory-order sequential sum, then /4
    float sb = __fadd_rn(__fadd_rn(__fadd_rn(CB[0], CB[1]), CB[2]), CB[3]);
    float sr = __fadd_rn(__fadd_rn(__fadd_rn(CR[0], CR[1]), CR[2]), CR[3]);
    Cbs[qy][qx] = __fdiv_rn(sb, 4.0f);
    Crs[qy][qx] = __fdiv_rn(sr, 4.0f);
  }
  __syncthreads();

  // 96 blocks: 0..63 Y (8x8 grid), 64..79 Cb (4x4), 80..95 Cr (4x4).
  // ---- phase 2a: einsum-FMA DCT (k=(x,y) seq) + quant + diff_round + deq ----
  #pragma unroll
  for (int it = 0; it < 3; ++it) {
    int s = tid + it * 256;
    int bk = s >> 3, u = s & 7;
    float* base; int stride; const float (*QT)[8];
    if (bk < 64) { base = &Ys[(bk >> 3) * 8][(bk & 7) * 8]; stride = 68; QT = QYT; }
    else if (bk < 80) { int c = bk - 64; base = &Cbs[(c >> 2) * 8][(c & 3) * 8]; stride = 36; QT = QCT; }
    else { int c = bk - 80; base = &Crs[(c >> 2) * 8][(c & 3) * 8]; stride = 36; QT = QCT; }

    float acc[8] = {0,0,0,0,0,0,0,0};
    #pragma unroll
    for (int xx = 0; xx < 8; ++xx) {
      float cux = Cs[xx * 8 + u];                  // _COS[x][u]
      const float* rowp = base + xx * stride;
      #pragma unroll
      for (int yy = 0; yy < 8; ++yy) {
        float pm = __fsub_rn(rowp[yy], 128.0f);
        #pragma unroll
        for (int v = 0; v < 8; ++v)
          acc[v] = __fmaf_rn(pm, __fmul_rn(cux, Cs[yy * 8 + v]), acc[v]);
      }
    }
    float au = alphaf(u);
    float e[8];
    #pragma unroll
    for (int v = 0; v < 8; ++v) {
      float av  = alphaf(v);
      float ao  = __fmul_rn(au, av);               // ALPHA_OUTER entry
      float sc  = __fmul_rn(ao, 0.25f);            // SCALE entry
      float qd  = __fmul_rn(QT[u][v], 0.4f);       // table * f32(0.4)
      float Sp  = __fmul_rn(sc, acc[v]);           // SCALE * einsum
      float qv  = __fdiv_rn(Sp, qd);
      float r   = rintf(qv);                       // np.round (half-even)
      float dd  = __fsub_rn(qv, r);
      float c3  = __fmul_rn(__fmul_rn(dd, dd), dd);
      float d   = __fadd_rn(r, c3);                // diff_round
      e[v] = __fmul_rn(__fmul_rn(d, qd), ao);      // dequant, then * AO
    }
    #pragma unroll
    for (int v = 0; v < 8; ++v) base[u * stride + v] = e[v];  // in place (same-wave block)
  }
  __syncthreads();

  // ---- phase 2b: einsum-FMA IDCT (k=(x,y) seq), *0.25, +128 ----
  #pragma unroll
  for (int it = 0; it < 3; ++it) {
    int s = tid + it * 256;
    int bk = s >> 3, us = s & 7;
    float* base; int stride;
    if (bk < 64) { base = &Ys[(bk >> 3) * 8][(bk & 7) * 8]; stride = 68; }
    else if (bk < 80) { int c = bk - 64; base = &Cbs[(c >> 2) * 8][(c & 3) * 8]; stride = 36; }
    else { int c = bk - 80; base = &Crs[(c >> 2) * 8][(c & 3) * 8]; stride = 36; }

    float acc[8] = {0,0,0,0,0,0,0,0};
    #pragma unroll
    for (int xx = 0; xx < 8; ++xx) {
      float cux = Cs[us * 8 + xx];                 // _COS[us][x]
      const float* rowp = base + xx * stride;
      #pragma unroll
      for (int yy = 0; yy < 8; ++yy) {
        float ev = rowp[yy];
        #pragma unroll
        for (int vs = 0; vs < 8; ++vs)
          acc[vs] = __fmaf_rn(ev, __fmul_rn(cux, Cs[vs * 8 + yy]), acc[vs]);
      }
    }
    float pix[8];
    #pragma unroll
    for (int vs = 0; vs < 8; ++vs)
      pix[vs] = __fadd_rn(__fmul_rn(0.25f, acc[vs]), 128.0f);
    #pragma unroll
    for (int vs = 0; vs < 8; ++vs) base[us * stride + vs] = pix[vs];
  }
  __syncthreads();

  // ---- phase 3: upsample, +(-128), sgemm-FMA YCC->RGB, clip, /255 ----
  float* oR = out + (size_t)(b * 3 + 0) * PLANE;
  float* oG = out + (size_t)(b * 3 + 1) * PLANE;
  float* oB = out + (size_t)(b * 3 + 2) * PLANE;
  #pragma unroll
  for (int i = 0; i < 4; ++i) {
    int g = tid + i * 256;           // 64 rows x 16 groups of 4 px
    int py = g >> 4, pxg = g & 15;
    int col = pxg * 4;
    float yv[4];
    #pragma unroll
    for (int j = 0; j < 4; ++j) yv[j] = Ys[py][col + j];

    int cy = py >> 1, cx = 2 * pxg;
    float cb0 = __fadd_rn(Cbs[cy][cx],     -128.0f);
    float cb1 = __fadd_rn(Cbs[cy][cx + 1], -128.0f);
    float cr0 = __fadd_rn(Crs[cy][cx],     -128.0f);
    float cr1 = __fadd_rn(Crs[cy][cx + 1], -128.0f);
    float cb[4] = {cb0, cb0, cb1, cb1};
    float cr[4] = {cr0, cr0, cr1, cr1};

    float rr[4], gg[4], bb[4];
    #pragma unroll
    for (int j = 0; j < 4; ++j) {
      // sgemm K=3, m[*][0]=Y coeff 1.0 (exact), zeros exact via fma skip
      float R  = __fmaf_rn(cr[j], 1.402f, yv[j]);
      float G  = __fmaf_rn(cr[j], -0.714136f, __fmaf_rn(cb[j], -0.344136f, yv[j]));
      float Bv = __fmaf_rn(cb[j], 1.772f, yv[j]);
      R  = fminf(fmaxf(R,  0.0f), 255.0f);
      G  = fminf(fmaxf(G,  0.0f), 255.0f);
      Bv = fminf(fmaxf(Bv, 0.0f), 255.0f);
      rr[j] = __fdiv_rn(R,  255.0f);
      gg[j] = __fdiv_rn(G,  255.0f);
      bb[j] = __fdiv_rn(Bv, 255.0f);
    }
    size_t o = (size_t)(row0 + py) * WW + (col0 + col);
    *(float4*)(oR + o) = make_float4(rr[0], rr[1], rr[2], rr[3]);
    *(float4*)(oG + o) = make_float4(gg[0], gg[1], gg[2], gg[3]);
    *(float4*)(oB + o) = make_float4(bb[0], bb[1], bb[2], bb[3]);
  }
}

extern "C" void kernel_launch(void* const* d_in, const int* in_sizes, int n_in,
                              void* d_out, int out_size, void* d_ws, size_t ws_size,
                              hipStream_t stream) {
  (void)in_sizes; (void)n_in; (void)d_ws; (void)ws_size; (void)out_size;
  const float* x   = (const float*)d_in[0];
  const float* src = (const float*)d_in[1];
  float* out = (float*)d_out;

  diffjpeg_kernel<<<dim3(BATCH * 64), dim3(256), 0, stream>>>(x, out);
  hipMemcpyAsync(out + NELEM, src, NELEM * sizeof(float),
                 hipMemcpyDeviceToDevice, stream);
}

// Round 5
// 69.887 us; speedup vs baseline: 1.0471x; 1.0471x over previous
//
#include <hip/hip_runtime.h>
#include <math.h>

#define BATCH 16
#define HH 512
#define WW 512
#define PLANE ((size_t)HH * WW)
#define NELEM ((size_t)BATCH * 3 * PLANE)

// Quant divisor tables, reference's .T applied: QT[u][v] (small ints, exact f32)
__constant__ float QYT[8][8] = {
  {16,12,14,14,18,24,49,72},
  {11,12,13,17,22,35,64,92},
  {10,14,16,22,37,55,78,95},
  {16,19,24,29,56,64,87,98},
  {24,26,40,51,68,81,103,112},
  {40,58,57,87,109,104,121,100},
  {51,60,69,80,103,113,120,103},
  {61,55,56,62,77,92,101,99},
};
__constant__ float QCT[8][8] = {
  {17,18,24,47,99,99,99,99},
  {18,21,26,66,99,99,99,99},
  {24,26,56,99,99,99,99,99},
  {47,66,99,99,99,99,99,99},
  {99,99,99,99,99,99,99,99},
  {99,99,99,99,99,99,99,99},
  {99,99,99,99,99,99,99,99},
  {99,99,99,99,99,99,99,99},
};

__device__ __forceinline__ float alphaf(int i) {
  return (i == 0) ? 0.70710678118654746f : 1.0f;  // f32(1/np.sqrt(2))
}

// 128 threads per WG, 32x64-pixel tile. Grid = 16 images * 128 tiles = 2048.
// LDS ~13.3 KB -> 8 WGs/CU resident (matches the 16-wave VGPR cap).
extern "C" __global__ __launch_bounds__(128)
void diffjpeg_kernel(const float* __restrict__ x, float* __restrict__ out) {
  __shared__ float Ys[32][68];   // 32x64 luma tile, padded stride
  __shared__ float Cbs[16][36];  // 16x32 chroma tiles
  __shared__ float Crs[16][36];
  __shared__ float Cs[64];       // Cs[a*8+b] = f32 _COS[a][b]

  const int blk = blockIdx.x;
  const int b   = blk >> 7;          // image 0..15
  const int t   = blk & 127;         // tile 0..127 (16 rows x 8 cols of tiles)
  const int trow = t >> 3, tcol = t & 7;
  const int row0 = trow * 32, col0 = tcol * 64;
  const int tid = threadIdx.x;

  // ---- phase 0: numpy-bitwise cos table (one wave) ----
  if (tid < 64) {
    int a = tid >> 3, bb = tid & 7;
    float t2 = (float)((2 * a + 1) * bb);
    float t3 = __fmul_rn(t2, 3.14159265358979323846f);
    float t4 = __fmul_rn(t3, 0.0625f);
    Cs[tid] = (float)cos((double)t4);
  }

  const float* Rp = x + (size_t)(b * 3 + 0) * PLANE;
  const float* Gp = x + (size_t)(b * 3 + 1) * PLANE;
  const float* Bp = x + (size_t)(b * 3 + 2) * PLANE;

  // ---- phase 1: x*255 -> sgemm-FMA YCC -> +128 -> 2x2 mean ----
  #pragma unroll
  for (int i = 0; i < 4; ++i) {
    int q  = tid + i * 128;          // quad 0..511 (16x32 quads of 2x2 px)
    int qy = q >> 5, qx = q & 31;
    size_t base = (size_t)(row0 + 2 * qy) * WW + (col0 + 2 * qx);
    float2 r0 = *(const float2*)(Rp + base);
    float2 r1 = *(const float2*)(Rp + base + WW);
    float2 g0 = *(const float2*)(Gp + base);
    float2 g1 = *(const float2*)(Gp + base + WW);
    float2 b0 = *(const float2*)(Bp + base);
    float2 b1 = *(const float2*)(Bp + base + WW);

    float rf[4] = {r0.x, r0.y, r1.x, r1.y};
    float gf[4] = {g0.x, g0.y, g1.x, g1.y};
    float bf[4] = {b0.x, b0.y, b1.x, b1.y};
    float Yv[4], CB[4], CR[4];
    #pragma unroll
    for (int j = 0; j < 4; ++j) {
      float R  = __fmul_rn(rf[j], 255.0f);
      float G  = __fmul_rn(gf[j], 255.0f);
      float Bv = __fmul_rn(bf[j], 255.0f);
      Yv[j] = __fmaf_rn(Bv, 0.114f, __fmaf_rn(G, 0.587f, __fmul_rn(R, 0.299f)));
      CB[j] = __fadd_rn(
          __fmaf_rn(Bv, 0.5f, __fmaf_rn(G, -0.331264f, __fmul_rn(R, -0.168736f))),
          128.0f);
      CR[j] = __fadd_rn(
          __fmaf_rn(Bv, -0.081312f, __fmaf_rn(G, -0.418688f, __fmul_rn(R, 0.5f))),
          128.0f);
    }

    Ys[2 * qy    ][2 * qx]     = Yv[0];
    Ys[2 * qy    ][2 * qx + 1] = Yv[1];
    Ys[2 * qy + 1][2 * qx]     = Yv[2];
    Ys[2 * qy + 1][2 * qx + 1] = Yv[3];

    float sb = __fadd_rn(__fadd_rn(__fadd_rn(CB[0], CB[1]), CB[2]), CB[3]);
    float sr = __fadd_rn(__fadd_rn(__fadd_rn(CR[0], CR[1]), CR[2]), CR[3]);
    Cbs[qy][qx] = __fdiv_rn(sb, 4.0f);
    Crs[qy][qx] = __fdiv_rn(sr, 4.0f);
  }
  __syncthreads();

  // 48 blocks: 0..31 Y (4x8 grid), 32..39 Cb (2x4), 40..47 Cr (2x4).
  // Thread owns OUTPUT COLUMN v (lane = 8*blk_sub+v): writes land 2-way
  // bank-aliased (free) instead of 8-way. Accumulator chains identical.
  // ---- phase 2a: einsum-FMA DCT + quant + diff_round + dequant ----
  #pragma unroll
  for (int it = 0; it < 3; ++it) {
    int s = tid + it * 128;          // 0..383
    int bk = s >> 3, v = s & 7;
    float* base; int stride; const float (*QT)[8];
    if (bk < 32) { base = &Ys[(bk >> 3) * 8][(bk & 7) * 8]; stride = 68; QT = QYT; }
    else if (bk < 40) { int c = bk - 32; base = &Cbs[(c >> 2) * 8][(c & 3) * 8]; stride = 36; QT = QCT; }
    else { int c = bk - 40; base = &Crs[(c >> 2) * 8][(c & 3) * 8]; stride = 36; QT = QCT; }

    float cyv_own = 0.f;  // silence unused warn path
    (void)cyv_own;
    float acc[8] = {0,0,0,0,0,0,0,0};
    #pragma unroll
    for (int xx = 0; xx < 8; ++xx) {
      const float* rowp = base + xx * stride;
      #pragma unroll
      for (int yy = 0; yy < 8; ++yy) {
        float pm = __fsub_rn(rowp[yy], 128.0f);
        float cyv = Cs[yy * 8 + v];
        #pragma unroll
        for (int u = 0; u < 8; ++u)
          acc[u] = __fmaf_rn(pm, __fmul_rn(Cs[xx * 8 + u], cyv), acc[u]);
      }
    }
    float av = alphaf(v);
    float e[8];
    #pragma unroll
    for (int u = 0; u < 8; ++u) {
      float au  = alphaf(u);
      float ao  = __fmul_rn(au, av);
      float sc  = __fmul_rn(ao, 0.25f);
      float qd  = __fmul_rn(QT[u][v], 0.4f);
      float Sp  = __fmul_rn(sc, acc[u]);
      float qv  = __fdiv_rn(Sp, qd);
      float r   = rintf(qv);
      float dd  = __fsub_rn(qv, r);
      float c3  = __fmul_rn(__fmul_rn(dd, dd), dd);
      float d   = __fadd_rn(r, c3);
      e[u] = __fmul_rn(__fmul_rn(d, qd), ao);
    }
    #pragma unroll
    for (int u = 0; u < 8; ++u) base[u * stride + v] = e[u];
  }
  __syncthreads();

  // ---- phase 2b: einsum-FMA IDCT, *0.25, +128 (thread owns column vs) ----
  #pragma unroll
  for (int it = 0; it < 3; ++it) {
    int s = tid + it * 128;
    int bk = s >> 3, vs = s & 7;
    float* base; int stride;
    if (bk < 32) { base = &Ys[(bk >> 3) * 8][(bk & 7) * 8]; stride = 68; }
    else if (bk < 40) { int c = bk - 32; base = &Cbs[(c >> 2) * 8][(c & 3) * 8]; stride = 36; }
    else { int c = bk - 40; base = &Crs[(c >> 2) * 8][(c & 3) * 8]; stride = 36; }

    float acc[8] = {0,0,0,0,0,0,0,0};
    #pragma unroll
    for (int xx = 0; xx < 8; ++xx) {
      const float* rowp = base + xx * stride;
      #pragma unroll
      for (int yy = 0; yy < 8; ++yy) {
        float ev = rowp[yy];
        float cvy = Cs[vs * 8 + yy];
        #pragma unroll
        for (int us = 0; us < 8; ++us)
          acc[us] = __fmaf_rn(ev, __fmul_rn(Cs[us * 8 + xx], cvy), acc[us]);
      }
    }
    float pix[8];
    #pragma unroll
    for (int us = 0; us < 8; ++us)
      pix[us] = __fadd_rn(__fmul_rn(0.25f, acc[us]), 128.0f);
    #pragma unroll
    for (int us = 0; us < 8; ++us) base[us * stride + vs] = pix[us];
  }
  __syncthreads();

  // ---- phase 3: upsample, -128, sgemm-FMA YCC->RGB, clip, /255 ----
  float* oR = out + (size_t)(b * 3 + 0) * PLANE;
  float* oG = out + (size_t)(b * 3 + 1) * PLANE;
  float* oB = out + (size_t)(b * 3 + 2) * PLANE;
  #pragma unroll
  for (int i = 0; i < 4; ++i) {
    int g = tid + i * 128;           // 32 rows x 16 groups of 4 px
    int py = g >> 4, pxg = g & 15;
    int col = pxg * 4;
    float yv[4];
    #pragma unroll
    for (int j = 0; j < 4; ++j) yv[j] = Ys[py][col + j];

    int cy = py >> 1, cx = 2 * pxg;
    float cb0 = __fadd_rn(Cbs[cy][cx],     -128.0f);
    float cb1 = __fadd_rn(Cbs[cy][cx + 1], -128.0f);
    float cr0 = __fadd_rn(Crs[cy][cx],     -128.0f);
    float cr1 = __fadd_rn(Crs[cy][cx + 1], -128.0f);
    float cb[4] = {cb0, cb0, cb1, cb1};
    float cr[4] = {cr0, cr0, cr1, cr1};

    float rr[4], gg[4], bb[4];
    #pragma unroll
    for (int j = 0; j < 4; ++j) {
      float R  = __fmaf_rn(cr[j], 1.402f, yv[j]);
      float G  = __fmaf_rn(cr[j], -0.714136f, __fmaf_rn(cb[j], -0.344136f, yv[j]));
      float Bv = __fmaf_rn(cb[j], 1.772f, yv[j]);
      R  = fminf(fmaxf(R,  0.0f), 255.0f);
      G  = fminf(fmaxf(G,  0.0f), 255.0f);
      Bv = fminf(fmaxf(Bv, 0.0f), 255.0f);
      rr[j] = __fdiv_rn(R,  255.0f);
      gg[j] = __fdiv_rn(G,  255.0f);
      bb[j] = __fdiv_rn(Bv, 255.0f);
    }
    size_t o = (size_t)(row0 + py) * WW + (col0 + col);
    *(float4*)(oR + o) = make_float4(rr[0], rr[1], rr[2], rr[3]);
    *(float4*)(oG + o) = make_float4(gg[0], gg[1], gg[2], gg[3]);
    *(float4*)(oB + o) = make_float4(bb[0], bb[1], bb[2], bb[3]);
  }
}

extern "C" void kernel_launch(void* const* d_in, const int* in_sizes, int n_in,
                              void* d_out, int out_size, void* d_ws, size_t ws_size,
                              hipStream_t stream) {
  (void)in_sizes; (void)n_in; (void)d_ws; (void)ws_size; (void)out_size;
  const float* x   = (const float*)d_in[0];
  const float* src = (const float*)d_in[1];
  float* out = (float*)d_out;

  diffjpeg_kernel<<<dim3(BATCH * 128), dim3(128), 0, stream>>>(x, out);
  hipMemcpyAsync(out + NELEM, src, NELEM * sizeof(float),
                 hipMemcpyDeviceToDevice, stream);
}

// Round 6
// 52.414 us; speedup vs baseline: 1.3961x; 1.3334x over previous
//
#include <hip/hip_runtime.h>
#include <math.h>

#define BATCH 16
#define HH 512
#define WW 512
#define PLANE ((size_t)HH * WW)
#define NELEM ((size_t)BATCH * 3 * PLANE)

// Quant divisor tables, reference's .T applied: QT[u][v] (small ints, exact f32)
__constant__ float QYT[8][8] = {
  {16,12,14,14,18,24,49,72},
  {11,12,13,17,22,35,64,92},
  {10,14,16,22,37,55,78,95},
  {16,19,24,29,56,64,87,98},
  {24,26,40,51,68,81,103,112},
  {40,58,57,87,109,104,121,100},
  {51,60,69,80,103,113,120,103},
  {61,55,56,62,77,92,101,99},
};
__constant__ float QCT[8][8] = {
  {17,18,24,47,99,99,99,99},
  {18,21,26,66,99,99,99,99},
  {24,26,56,99,99,99,99,99},
  {47,66,99,99,99,99,99,99},
  {99,99,99,99,99,99,99,99},
  {99,99,99,99,99,99,99,99},
  {99,99,99,99,99,99,99,99},
  {99,99,99,99,99,99,99,99},
};

// Blocked LDS: Blk[bk][68] (stride 68 floats = 272B, 16B-aligned rows).
// bk 0..31 = Y blocks (4 rows x 8 cols of the 32x64 tile),
// bk 32..39 = Cb (2x4), bk 40..47 = Cr (2x4). Element offset = x*8+y.
extern "C" __global__ __launch_bounds__(128)
void diffjpeg_kernel(const float* __restrict__ x, const float* __restrict__ src,
                     float* __restrict__ out) {
  __shared__ float Blk[48][68];
  __shared__ float Cs[64];   // Cs[a*8+b] = f32 _COS[a][b] (numpy bit-match)

  const int blk = blockIdx.x;
  const int b   = blk >> 7;          // image 0..15
  const int t   = blk & 127;         // tile (16 rows x 8 cols of 32x64 tiles)
  const int trow = t >> 3, tcol = t & 7;
  const int row0 = trow * 32, col0 = tcol * 64;
  const int tid = threadIdx.x;

  // ---- phase 0: numpy-bitwise cos table ----
  if (tid < 64) {
    int a = tid >> 3, bb = tid & 7;
    float t2 = (float)((2 * a + 1) * bb);
    float t3 = __fmul_rn(t2, 3.14159265358979323846f);
    float t4 = __fmul_rn(t3, 0.0625f);
    Cs[tid] = (float)cos((double)t4);
  }

  const float* Rp = x + (size_t)(b * 3 + 0) * PLANE;
  const float* Gp = x + (size_t)(b * 3 + 1) * PLANE;
  const float* Bp = x + (size_t)(b * 3 + 2) * PLANE;

  // ---- phase 1: x*255 -> sgemm-FMA YCC (+128 chroma) -> 2x2 mean -> -128 ----
  // (the -128 DCT-input shift is applied here: same op on same value, bit-exact)
  #pragma unroll
  for (int i = 0; i < 4; ++i) {
    int q  = tid + i * 128;          // quad 0..511 (16 rows x 32 cols of 2x2 px)
    int qy = q >> 5, qx = q & 31;
    size_t base = (size_t)(row0 + 2 * qy) * WW + (col0 + 2 * qx);
    float2 r0 = *(const float2*)(Rp + base);
    float2 r1 = *(const float2*)(Rp + base + WW);
    float2 g0 = *(const float2*)(Gp + base);
    float2 g1 = *(const float2*)(Gp + base + WW);
    float2 b0 = *(const float2*)(Bp + base);
    float2 b1 = *(const float2*)(Bp + base + WW);

    float rf[4] = {r0.x, r0.y, r1.x, r1.y};
    float gf[4] = {g0.x, g0.y, g1.x, g1.y};
    float bf[4] = {b0.x, b0.y, b1.x, b1.y};
    float Ym[4], CB[4], CR[4];
    #pragma unroll
    for (int j = 0; j < 4; ++j) {
      float R  = __fmul_rn(rf[j], 255.0f);
      float G  = __fmul_rn(gf[j], 255.0f);
      float Bv = __fmul_rn(bf[j], 255.0f);
      float Yv = __fmaf_rn(Bv, 0.114f, __fmaf_rn(G, 0.587f, __fmul_rn(R, 0.299f)));
      Ym[j] = __fsub_rn(Yv, 128.0f);               // DCT input shift (moved)
      CB[j] = __fadd_rn(
          __fmaf_rn(Bv, 0.5f, __fmaf_rn(G, -0.331264f, __fmul_rn(R, -0.168736f))),
          128.0f);
      CR[j] = __fadd_rn(
          __fmaf_rn(Bv, -0.081312f, __fmaf_rn(G, -0.418688f, __fmul_rn(R, 0.5f))),
          128.0f);
    }

    int ybk = (qy >> 2) * 8 + (qx >> 2);
    int xin = (qy & 3) * 2, yin = (qx & 3) * 2;
    float* Pb = Blk[ybk];
    *(float2*)&Pb[xin * 8 + yin]       = make_float2(Ym[0], Ym[1]);
    *(float2*)&Pb[(xin + 1) * 8 + yin] = make_float2(Ym[2], Ym[3]);

    float sb = __fadd_rn(__fadd_rn(__fadd_rn(CB[0], CB[1]), CB[2]), CB[3]);
    float sr = __fadd_rn(__fadd_rn(__fadd_rn(CR[0], CR[1]), CR[2]), CR[3]);
    int cbk = 32 + (qy >> 3) * 4 + (qx >> 3);
    int coff = (qy & 7) * 8 + (qx & 7);
    Blk[cbk][coff]     = __fsub_rn(__fdiv_rn(sb, 4.0f), 128.0f);  // mean,-128
    Blk[cbk + 8][coff] = __fsub_rn(__fdiv_rn(sr, 4.0f), 128.0f);
  }
  __syncthreads();

  // ---- phase 2: lane owns coefficient (u,v); wave owns 24 blocks ----
  const int w    = tid >> 6;
  const int lane = tid & 63;
  const int u = lane >> 3, v = lane & 7;
  const float au = (u == 0) ? 0.70710678118654746f : 1.0f;
  const float av = (v == 0) ? 0.70710678118654746f : 1.0f;
  const float ao  = __fmul_rn(au, av);        // ALPHA_OUTER[u][v]
  const float sc  = __fmul_rn(ao, 0.25f);     // SCALE[u][v]
  const float qdY = __fmul_rn(QYT[u][v], 0.4f);
  const float qdC = __fmul_rn(QCT[u][v], 0.4f);
  const int  bk0  = w * 24;

  float Wf[64];
  {
    float cu_[8], cv_[8];
    #pragma unroll
    for (int k = 0; k < 8; ++k) { cu_[k] = Cs[k * 8 + u]; cv_[k] = Cs[k * 8 + v]; }
    #pragma unroll
    for (int xx = 0; xx < 8; ++xx)
      #pragma unroll
      for (int yy = 0; yy < 8; ++yy)
        Wf[xx * 8 + yy] = __fmul_rn(cu_[xx], cv_[yy]);  // f32 DCT_T[x][y][u][v]
  }

  // ---- 2a: DCT + quant + diff_round + dequant(*AO), in place ----
  for (int pb = 0; pb < 12; ++pb) {
    int bkA = bk0 + 2 * pb, bkB = bkA + 1;
    const float* A = Blk[bkA];
    const float* C = Blk[bkB];
    float accA = 0.f, accB = 0.f;
    #pragma unroll
    for (int k4 = 0; k4 < 16; ++k4) {
      float4 a = *(const float4*)(A + 4 * k4);   // wave-uniform broadcast
      float4 c = *(const float4*)(C + 4 * k4);
      accA = __fmaf_rn(a.x, Wf[4 * k4 + 0], accA);
      accB = __fmaf_rn(c.x, Wf[4 * k4 + 0], accB);
      accA = __fmaf_rn(a.y, Wf[4 * k4 + 1], accA);
      accB = __fmaf_rn(c.y, Wf[4 * k4 + 1], accB);
      accA = __fmaf_rn(a.z, Wf[4 * k4 + 2], accA);
      accB = __fmaf_rn(c.z, Wf[4 * k4 + 2], accB);
      accA = __fmaf_rn(a.w, Wf[4 * k4 + 3], accA);
      accB = __fmaf_rn(c.w, Wf[4 * k4 + 3], accB);
    }
    float qd = (bkA < 32) ? qdY : qdC;
    float SpA = __fmul_rn(sc, accA);
    float SpB = __fmul_rn(sc, accB);
    float qvA = __fdiv_rn(SpA, qd);
    float qvB = __fdiv_rn(SpB, qd);
    float rA = rintf(qvA), rB = rintf(qvB);
    float dA = __fsub_rn(qvA, rA), dB = __fsub_rn(qvB, rB);
    float eA = __fadd_rn(rA, __fmul_rn(__fmul_rn(dA, dA), dA));
    float eB = __fadd_rn(rB, __fmul_rn(__fmul_rn(dB, dB), dB));
    Blk[bkA][lane] = __fmul_rn(__fmul_rn(eA, qd), ao);  // lane = u*8+v
    Blk[bkB][lane] = __fmul_rn(__fmul_rn(eB, qd), ao);
  }

  // ---- 2b: IDCT (lane owns spatial (u,v)), *0.25, +128, in place ----
  {
    float cu_[8], cv_[8];
    #pragma unroll
    for (int k = 0; k < 8; ++k) { cu_[k] = Cs[u * 8 + k]; cv_[k] = Cs[v * 8 + k]; }
    #pragma unroll
    for (int xx = 0; xx < 8; ++xx)
      #pragma unroll
      for (int yy = 0; yy < 8; ++yy)
        Wf[xx * 8 + yy] = __fmul_rn(cu_[xx], cv_[yy]);  // f32 IDCT_T[x][y][u][v]
  }
  for (int pb = 0; pb < 12; ++pb) {
    int bkA = bk0 + 2 * pb, bkB = bkA + 1;
    const float* A = Blk[bkA];
    const float* C = Blk[bkB];
    float accA = 0.f, accB = 0.f;
    #pragma unroll
    for (int k4 = 0; k4 < 16; ++k4) {
      float4 a = *(const float4*)(A + 4 * k4);
      float4 c = *(const float4*)(C + 4 * k4);
      accA = __fmaf_rn(a.x, Wf[4 * k4 + 0], accA);
      accB = __fmaf_rn(c.x, Wf[4 * k4 + 0], accB);
      accA = __fmaf_rn(a.y, Wf[4 * k4 + 1], accA);
      accB = __fmaf_rn(c.y, Wf[4 * k4 + 1], accB);
      accA = __fmaf_rn(a.z, Wf[4 * k4 + 2], accA);
      accB = __fmaf_rn(c.z, Wf[4 * k4 + 2], accB);
      accA = __fmaf_rn(a.w, Wf[4 * k4 + 3], accA);
      accB = __fmaf_rn(c.w, Wf[4 * k4 + 3], accB);
    }
    Blk[bkA][lane] = __fadd_rn(__fmul_rn(0.25f, accA), 128.0f);
    Blk[bkB][lane] = __fadd_rn(__fmul_rn(0.25f, accB), 128.0f);
  }
  __syncthreads();

  // ---- phase 3: upsample, -128, sgemm-FMA YCC->RGB, clip, /255, store ----
  float* oR = out + (size_t)(b * 3 + 0) * PLANE;
  float* oG = out + (size_t)(b * 3 + 1) * PLANE;
  float* oB = out + (size_t)(b * 3 + 2) * PLANE;
  #pragma unroll
  for (int i = 0; i < 4; ++i) {
    int g = tid + i * 128;           // 32 rows x 16 groups of 4 px
    int py = g >> 4, pxg = g & 15;
    int col = pxg * 4;
    int ybk = (py >> 3) * 8 + (col >> 3);
    int yoff = (py & 7) * 8 + (col & 7);
    float4 yv4 = *(const float4*)&Blk[ybk][yoff];
    float yv[4] = {yv4.x, yv4.y, yv4.z, yv4.w};

    int cy = py >> 1, cx = 2 * pxg;
    int cbk = 32 + (cy >> 3) * 4 + (cx >> 3);
    int coff = (cy & 7) * 8 + (cx & 7);
    float2 cbv = *(const float2*)&Blk[cbk][coff];
    float2 crv = *(const float2*)&Blk[cbk + 8][coff];
    float cb0 = __fadd_rn(cbv.x, -128.0f);
    float cb1 = __fadd_rn(cbv.y, -128.0f);
    float cr0 = __fadd_rn(crv.x, -128.0f);
    float cr1 = __fadd_rn(crv.y, -128.0f);
    float cb[4] = {cb0, cb0, cb1, cb1};
    float cr[4] = {cr0, cr0, cr1, cr1};

    float rr[4], gg[4], bb[4];
    #pragma unroll
    for (int j = 0; j < 4; ++j) {
      float R  = __fmaf_rn(cr[j], 1.402f, yv[j]);
      float G  = __fmaf_rn(cr[j], -0.714136f, __fmaf_rn(cb[j], -0.344136f, yv[j]));
      float Bv = __fmaf_rn(cb[j], 1.772f, yv[j]);
      R  = fminf(fmaxf(R,  0.0f), 255.0f);
      G  = fminf(fmaxf(G,  0.0f), 255.0f);
      Bv = fminf(fmaxf(Bv, 0.0f), 255.0f);
      rr[j] = __fdiv_rn(R,  255.0f);
      gg[j] = __fdiv_rn(G,  255.0f);
      bb[j] = __fdiv_rn(Bv, 255.0f);
    }
    size_t o = (size_t)(row0 + py) * WW + (col0 + col);
    *(float4*)(oR + o) = make_float4(rr[0], rr[1], rr[2], rr[3]);
    *(float4*)(oG + o) = make_float4(gg[0], gg[1], gg[2], gg[3]);
    *(float4*)(oB + o) = make_float4(bb[0], bb[1], bb[2], bb[3]);
  }

  // ---- phase 4: fold the source_image pass-through copy (tuple elem 1) ----
  #pragma unroll
  for (int p = 0; p < 3; ++p) {
    const float* Sp = src + (size_t)(b * 3 + p) * PLANE;
    float*       Op = out + NELEM + (size_t)(b * 3 + p) * PLANE;
    #pragma unroll
    for (int i = 0; i < 4; ++i) {
      int idx = tid + i * 128;       // 32 rows x 16 float4/row
      int r = idx >> 4, c4 = idx & 15;
      size_t o = (size_t)(row0 + r) * WW + col0 + c4 * 4;
      *(float4*)(Op + o) = *(const float4*)(Sp + o);
    }
  }
}

extern "C" void kernel_launch(void* const* d_in, const int* in_sizes, int n_in,
                              void* d_out, int out_size, void* d_ws, size_t ws_size,
                              hipStream_t stream) {
  (void)in_sizes; (void)n_in; (void)d_ws; (void)ws_size; (void)out_size;
  const float* x   = (const float*)d_in[0];
  const float* src = (const float*)d_in[1];
  float* out = (float*)d_out;

  diffjpeg_kernel<<<dim3(BATCH * 128), dim3(128), 0, stream>>>(x, src, out);
}